// Round 9
// baseline (2196.892 us; speedup 1.0000x reference)
//
#include <hip/hip_runtime.h>
#include <stdint.h>

#define B_ 8
#define D_ 128
#define T_ 4096
#define Q_ 30
#define C_ 1024

typedef __attribute__((ext_vector_type(8))) _Float16 half8;
typedef __attribute__((ext_vector_type(4))) float float4_;

// fp16 codebook, 960 sub-chunks (gs = q*32+s) of 32 codes x 128 dims = 8KB each,
// XOR-swizzled 16B granules, byte-identical to the LDS ring-slot image.
__device__ __align__(16) _Float16 g_half[(size_t)Q_*32*4096];

typedef __attribute__((address_space(3))) void lds_void;
typedef __attribute__((address_space(1))) const void gbl_void;
__device__ __forceinline__ void gld16(const void* g, void* l){
  __builtin_amdgcn_global_load_lds((gbl_void*)g, (lds_void*)l, 16, 0, 0);
}

// ---------------- prep 1: per-code ||c||^2, fp64 accumulation ----------------
__global__ void rvq_prep(const float* __restrict__ cb, float* __restrict__ sumsq){
  int g    = blockIdx.x*128 + (threadIdx.x>>1);
  int half = threadIdx.x & 1;
  const float* src = cb + (size_t)g*D_ + half*64;
  double s = 0.0;
#pragma unroll
  for (int i=0;i<64;i+=4){
    float4_ f = *(const float4_*)(src+i);
    s += (double)f.x*f.x + (double)f.y*f.y + (double)f.z*f.z + (double)f.w*f.w;
  }
  s += __shfl_xor(s, 1);
  if (!half) sumsq[g] = (float)s;
}

// ---------------- prep 2: build swizzled fp16 sub-chunk images ---------------
__global__ void rvq_split(const float* __restrict__ cb){
  const int gs   = blockIdx.x;            // sub-chunk 0..959
  const int tid  = threadIdx.x;
  const int crel = tid>>3;                // code in sub-chunk 0..31
  const int part = tid&7;                 // 2 granules per thread
  const int swz  = crel & 15;
  const float* src = cb + ((size_t)gs*32 + crel)*128 + part*16;
  _Float16* dst = g_half + ((size_t)gs<<12) + (crel<<7);
#pragma unroll
  for (int i=0;i<2;++i){
    float4_ f0 = *(const float4_*)(src + i*8);
    float4_ f1 = *(const float4_*)(src + i*8 + 4);
    half8 h;
    h[0]=(_Float16)f0.x; h[1]=(_Float16)f0.y; h[2]=(_Float16)f0.z; h[3]=(_Float16)f0.w;
    h[4]=(_Float16)f1.x; h[5]=(_Float16)f1.y; h[6]=(_Float16)f1.z; h[7]=(_Float16)f1.w;
    const int kg  = part*2 + i;
    const int kgs = kg ^ swz;
    *(half8*)&dst[kgs<<3] = h;
  }
}

// --- main: 30-step RVQ, barrier-free wave-private ring pipeline --------------
__global__ __launch_bounds__(256,1) void rvq_main(
    const float* __restrict__ x, const float* __restrict__ cb,
    const float* __restrict__ sumsq, double* __restrict__ lossAcc,
    float* __restrict__ out)
{
  __shared__ _Float16 sRing[4][3][4096];  // 96KB: per-wave private 3-slot ring
  __shared__ float sCS[4][32][34];        // per-wave top2 scores (stride 34: no conflicts)
  __shared__ int   sCI[4][32][34];
  __shared__ int   sI4[4][32][4];         // per-row top-4 ids
  __shared__ float sCcQ[1024];            // ||c||^2 for current q (only cross-wave data)

  const int tid  = threadIdx.x;
  const int wv   = tid>>6;
  const int ln   = tid&63;
  const int col  = ln&15;
  const int quad = ln>>4;
  const int blk  = blockIdx.x;
  const int b    = blk>>5;
  const int t0   = ((blk&31)<<7) + (wv<<5);

  // residual fp64, A-frag distribution: row = rt*16+col, dim = kc*32+quad*8+j
  double rmast[2][4][8];
#pragma unroll
  for (int rt=0;rt<2;++rt){
    const int t = t0 + rt*16 + col;
#pragma unroll
    for (int kc=0;kc<4;++kc)
#pragma unroll
      for (int j=0;j<8;++j){
        const int d = kc*32 + quad*8 + j;
        rmast[rt][kc][j] = (double)x[((size_t)b*D_ + d)*T_ + t];
      }
  }

  half8 ah[2][4];
  auto makeAB = [&](){
#pragma unroll
    for (int rt=0;rt<2;++rt)
#pragma unroll
      for (int kc=0;kc<4;++kc){
        half8 h;
#pragma unroll
        for (int j=0;j<8;++j) h[j] = (_Float16)(float)rmast[rt][kc][j];
        ah[rt][kc] = h;
      }
  };
  makeAB();

  // wave-private staging of one 8KB sub-chunk (8 x 16B DMA per lane)
  auto stage = [&](int gs){
    const char* gsrc = (const char*)g_half + ((size_t)gs<<13) + (ln<<4);
    char* ldst = (char*)&sRing[wv][gs%3][0] + (ln<<4);
#pragma unroll
    for (int it=0; it<8; ++it)
      gld16(gsrc + it*1024, ldst + it*1024);
  };

  for (int i=tid; i<1024; i+=256) sCcQ[i] = sumsq[i];
  stage(0); stage(1);
  __syncthreads();   // publishes sCcQ; drains prologue DMA (slots 0,1 valid)

  double lossd = 0.0;

  for (int q=0;q<Q_;++q){
    const float* cbq = cb + (size_t)q*C_*D_;

    float m1[2][4], m2[2][4]; int i1[2][4], i2[2][4];
#pragma unroll
    for (int rt=0;rt<2;++rt)
#pragma unroll
      for (int rg=0;rg<4;++rg){
        m1[rt][rg]=3.0e38f; i1[rt][rg]=0;
        m2[rt][rg]=3.0e38f; i2[rt][rg]=0;
      }

    for (int s=0; s<32; ++s){
      const int gs = q*32 + s;
      if (gs+2 < Q_*32){
        stage(gs+2);
        // FIFO vmcnt: all but the newest 16 (sub-chunks gs+1, gs+2) are done
        // => sub-chunk gs fully landed. Holds across q boundaries.
        asm volatile("s_waitcnt vmcnt(16)" ::: "memory");
      } else {
        asm volatile("s_waitcnt vmcnt(0)" ::: "memory");   // kernel tail only
      }
      const _Float16* base = &sRing[wv][gs%3][0];

      float4_ acc[2][2];
#pragma unroll
      for (int a=0;a<2;++a)
#pragma unroll
        for (int c2=0;c2<2;++c2) acc[a][c2] = (float4_){0.f,0.f,0.f,0.f};
#pragma unroll
      for (int kc=0;kc<4;++kc){
        const int kgs = ((kc<<2) + quad) ^ col;
        half8 bf[2];
#pragma unroll
        for (int ct=0;ct<2;++ct){
          const int n = ct*16 + col;
          bf[ct] = *(const half8*)&base[(n<<7) + (kgs<<3)];
        }
#pragma unroll
        for (int rt=0;rt<2;++rt)
#pragma unroll
          for (int ct=0;ct<2;++ct)
            acc[rt][ct] = __builtin_amdgcn_mfma_f32_16x16x32_f16(ah[rt][kc], bf[ct], acc[rt][ct], 0,0,0);
      }
#pragma unroll
      for (int ct=0;ct<2;++ct){
        const int cid = s*2 + ct;                      // global code = cid*16+col
        const float cc = sCcQ[(cid<<4) + col];
#pragma unroll
        for (int rt=0;rt<2;++rt)
#pragma unroll
          for (int rg=0;rg<4;++rg){
            float sc = fmaf(-2.0f, acc[rt][ct][rg], cc);
            if (sc < m1[rt][rg]) {
              m2[rt][rg]=m1[rt][rg]; i2[rt][rg]=i1[rt][rg];
              m1[rt][rg]=sc;         i1[rt][rg]=cid;
            } else if (sc < m2[rt][rg]) {
              m2[rt][rg]=sc;         i2[rt][rg]=cid;
            }
          }
      }
    }

    // ---- publish per-lane top-2 (wave-private; lockstep wave => no barrier) --
#pragma unroll
    for (int rt=0;rt<2;++rt)
#pragma unroll
      for (int rg=0;rg<4;++rg){
        const int row = rt*16 + quad*4 + rg;
        sCS[wv][row][col*2+0] = m1[rt][rg];  sCI[wv][row][col*2+0] = (i1[rt][rg]<<4)+col;
        sCS[wv][row][col*2+1] = m2[rt][rg];  sCI[wv][row][col*2+1] = (i2[rt][rg]<<4)+col;
      }

    // ---- lanes 0..31: scan own row's 32 entries -> sorted top-4 ----
    if (ln < 32){
      const int row = ln;
      float b0=3.0e38f,b1=3.0e38f,b2=3.0e38f,b3=3.0e38f;
      int   e0=0x7fffffff,e1=0x7fffffff,e2=0x7fffffff,e3=0x7fffffff;
#pragma unroll
      for (int c2=0;c2<32;++c2){
        const float sc = sCS[wv][row][c2];
        const int  id  = sCI[wv][row][c2];
        const bool l0 = (sc<b0)||(sc==b0&&id<e0);
        const bool l1 = (sc<b1)||(sc==b1&&id<e1);
        const bool l2 = (sc<b2)||(sc==b2&&id<e2);
        const bool l3 = (sc<b3)||(sc==b3&&id<e3);
        if (l3){
          b3 = l2 ? b2 : sc;  e3 = l2 ? e2 : id;
          if (l2){
            b2 = l1 ? b1 : sc;  e2 = l1 ? e1 : id;
            if (l1){
              b1 = l0 ? b0 : sc;  e1 = l0 ? e0 : id;
              if (l0){ b0 = sc; e0 = id; }
            }
          }
        }
      }
      sI4[wv][row][0]=e0; sI4[wv][row][1]=e1; sI4[wv][row][2]=e2; sI4[wv][row][3]=e3;
    }

    // ---- fp64 exact rescore of top-4, winner update (wave-private) ----------
#pragma unroll
    for (int rt=0;rt<2;++rt){
      const int m = rt*16 + col;
      double bestS = 1.0e300; int bestJ = 0x7fffffff;
#pragma unroll
      for (int cnd=0;cnd<4;++cnd){
        const int jj = sI4[wv][m][cnd];
        const float* p = cbq + ((size_t)jj<<7) + (quad<<3);
        double sd = 0.0;
#pragma unroll
        for (int kc=0;kc<4;++kc){
          float4_ a0 = *(const float4_*)(p + kc*32);
          float4_ a1 = *(const float4_*)(p + kc*32 + 4);
          float fv[8] = {a0.x,a0.y,a0.z,a0.w,a1.x,a1.y,a1.z,a1.w};
#pragma unroll
          for (int j=0;j<8;++j){
            double cd = (double)fv[j];
            sd += cd*(cd - 2.0*rmast[rt][kc][j]);
          }
        }
        sd += __shfl_xor(sd, 16); sd += __shfl_xor(sd, 32);
        if ((sd < bestS) || (sd == bestS && jj < bestJ)){ bestS = sd; bestJ = jj; }
      }
      const float* pw = cbq + ((size_t)bestJ<<7) + (quad<<3);
#pragma unroll
      for (int kc=0;kc<4;++kc){
        float4_ w0 = *(const float4_*)(pw + kc*32);
        float4_ w1 = *(const float4_*)(pw + kc*32 + 4);
        float fw[8] = {w0.x,w0.y,w0.z,w0.w,w1.x,w1.y,w1.z,w1.w};
#pragma unroll
        for (int j=0;j<8;++j){
          double rn = rmast[rt][kc][j] - (double)fw[j];
          rmast[rt][kc][j] = rn;
          lossd += rn*rn;
        }
      }
    }
    makeAB();
    if (q+1 < Q_){
      for (int i=tid; i<1024; i+=256) sCcQ[i] = sumsq[(q+1)*1024 + i];
      __syncthreads();   // ONLY per-q sync: publishes sCcQ(q+1)
    }
  }

  // ---- epilogue: quantized = x - r_final ----
#pragma unroll
  for (int rt=0;rt<2;++rt){
    const int t = t0 + rt*16 + col;
#pragma unroll
    for (int kc=0;kc<4;++kc)
#pragma unroll
      for (int j=0;j<8;++j){
        const int d = kc*32 + quad*8 + j;
        const size_t o = ((size_t)b*D_ + d)*T_ + t;
        out[o] = (float)((double)x[o] - rmast[rt][kc][j]);
      }
  }
#pragma unroll
  for (int mk=1; mk<64; mk<<=1) lossd += __shfl_xor(lossd, mk);
  if (ln==0) atomicAdd(lossAcc, lossd);
}

__global__ void rvq_fin(const double* __restrict__ lossAcc, float* __restrict__ out){
  out[(size_t)B_*D_*T_] = (float)(*lossAcc * (1.0/((double)B_*(double)D_*(double)T_)));
}

extern "C" void kernel_launch(void* const* d_in, const int* in_sizes, int n_in,
                              void* d_out, int out_size, void* d_ws, size_t ws_size,
                              hipStream_t stream) {
  const float* x  = (const float*)d_in[0];   // [B, D, T] fp32
  const float* cb = (const float*)d_in[1];   // [Q, C, D] fp32
  float* out      = (float*)d_out;           // [B*D*T] quantized + [1] loss
  double* lossAcc = (double*)d_ws;
  float*  sumsq   = (float*)((char*)d_ws + 256);   // Q*C floats

  hipMemsetAsync(d_ws, 0, 256, stream);
  rvq_prep <<<Q_*C_/128, 256, 0, stream>>>(cb, sumsq);
  rvq_split<<<Q_*32,     256, 0, stream>>>(cb);
  rvq_main <<<(B_*T_)/128, 256, 0, stream>>>(x, cb, sumsq, lossAcc, out);
  rvq_fin  <<<1, 1, 0, stream>>>(lossAcc, out);
}

// Round 10
// 1560.919 us; speedup vs baseline: 1.4074x; 1.4074x over previous
//
#include <hip/hip_runtime.h>
#include <stdint.h>

#define B_ 8
#define D_ 128
#define T_ 4096
#define Q_ 30
#define C_ 1024

typedef __attribute__((ext_vector_type(8))) _Float16 half8;
typedef __attribute__((ext_vector_type(4))) float float4_;

// row-major fp16 codebook image [Q*C][128] — B-fragments load straight from here.
__device__ __align__(16) _Float16 g_half[(size_t)Q_*C_*D_];

// ---------------- prep 1: per-code ||c||^2, fp64 accumulation ----------------
__global__ void rvq_prep(const float* __restrict__ cb, float* __restrict__ sumsq){
  int g    = blockIdx.x*128 + (threadIdx.x>>1);
  int half = threadIdx.x & 1;
  const float* src = cb + (size_t)g*D_ + half*64;
  double s = 0.0;
#pragma unroll
  for (int i=0;i<64;i+=4){
    float4_ f = *(const float4_*)(src+i);
    s += (double)f.x*f.x + (double)f.y*f.y + (double)f.z*f.z + (double)f.w*f.w;
  }
  s += __shfl_xor(s, 1);
  if (!half) sumsq[g] = (float)s;
}

// ---------------- prep 2: fp32 -> fp16 codebook, row-major -------------------
__global__ void rvq_h(const float* __restrict__ cb){
  const size_t i = ((size_t)blockIdx.x*256 + threadIdx.x)*8;
  float4_ f0 = *(const float4_*)(cb + i);
  float4_ f1 = *(const float4_*)(cb + i + 4);
  half8 h;
  h[0]=(_Float16)f0.x; h[1]=(_Float16)f0.y; h[2]=(_Float16)f0.z; h[3]=(_Float16)f0.w;
  h[4]=(_Float16)f1.x; h[5]=(_Float16)f1.y; h[6]=(_Float16)f1.z; h[7]=(_Float16)f1.w;
  *(half8*)(g_half + i) = h;
}

// --- main: 30-step RVQ, no LDS staging, no barriers, register pipeline -------
__global__ __launch_bounds__(256,1) void rvq_main(
    const float* __restrict__ x, const float* __restrict__ cb,
    const float* __restrict__ sumsq, double* __restrict__ lossAcc,
    float* __restrict__ out)
{
  __shared__ float sCS[4][32][34];   // per-wave packed top2 scores (stride 34)
  __shared__ int   sI4[4][32][4];    // per-row top-4 global code ids

  const int tid  = threadIdx.x;
  const int wv   = tid>>6;
  const int ln   = tid&63;
  const int col  = ln&15;
  const int quad = ln>>4;
  const int blk  = blockIdx.x;
  const int b    = blk>>5;
  const int t0   = ((blk&31)<<7) + (wv<<5);

  // residual fp64, A-frag distribution: row = rt*16+col, dim = kc*32+quad*8+j
  double rmast[2][4][8];
#pragma unroll
  for (int rt=0;rt<2;++rt){
    const int t = t0 + rt*16 + col;
#pragma unroll
    for (int kc=0;kc<4;++kc)
#pragma unroll
      for (int j=0;j<8;++j){
        const int d = kc*32 + quad*8 + j;
        rmast[rt][kc][j] = (double)x[((size_t)b*D_ + d)*T_ + t];
      }
  }

  half8 ah[2][4];
  auto makeAB = [&](){
#pragma unroll
    for (int rt=0;rt<2;++rt)
#pragma unroll
      for (int kc=0;kc<4;++kc){
        half8 h;
#pragma unroll
        for (int j=0;j<8;++j) h[j] = (_Float16)(float)rmast[rt][kc][j];
        ah[rt][kc] = h;
      }
  };
  makeAB();

  double lossd = 0.0;

  // register pipeline buffers: B-fragments + cc for one group (32 codes)
  half8 bufA[8], bufB[8];
  float ccA[2],  ccB[2];

  const _Float16* cbh0 = g_half;
  const float*    ssq0 = sumsq;

  auto loadGroup = [&](const _Float16* cbh, const float* ssq, int g, half8* Bv, float* cc){
#pragma unroll
    for (int kc=0;kc<4;++kc)
#pragma unroll
      for (int ct=0;ct<2;++ct){
        const int n = g*32 + ct*16 + col;
        Bv[kc*2+ct] = *(const half8*)(cbh + n*128 + kc*32 + quad*8);
      }
#pragma unroll
    for (int ct=0;ct<2;++ct)
      cc[ct] = ssq[(g*2+ct)*16 + col];
  };

  loadGroup(cbh0, ssq0, 0, bufA, ccA);   // prologue: q=0, group 0

  for (int q=0;q<Q_;++q){
    const float*    cbq = cb    + (size_t)q*C_*D_;
    const _Float16* cbh = g_half + (size_t)q*C_*D_;
    const float*    ssq = sumsq + q*C_;

    // packed top-2 per cell: score float with low 6 mantissa bits = cid (0..63)
    float p1[2][4], p2[2][4];
#pragma unroll
    for (int rt=0;rt<2;++rt)
#pragma unroll
      for (int rg=0;rg<4;++rg){ p1[rt][rg]=3.0e38f; p2[rt][rg]=3.0e38f; }

#pragma unroll
    for (int g=0; g<32; ++g){
      half8* cur = (g&1) ? bufB : bufA;
      float* ccc = (g&1) ? ccB  : ccA;
      // prefetch next group (codebook loads independent of residual —
      // cross-q prefetch of (q+1, group 0) overlaps the q-tail)
      if (g < 31){
        loadGroup(cbh, ssq, g+1, (g&1)?bufA:bufB, (g&1)?ccA:ccB);
      } else if (q+1 < Q_){
        loadGroup(cbh + C_*D_, ssq + C_, 0, (g&1)?bufA:bufB, (g&1)?ccA:ccB);
      }

      float4_ acc[2][2];
#pragma unroll
      for (int a=0;a<2;++a)
#pragma unroll
        for (int c2=0;c2<2;++c2) acc[a][c2] = (float4_){0.f,0.f,0.f,0.f};
#pragma unroll
      for (int kc=0;kc<4;++kc)
#pragma unroll
        for (int rt=0;rt<2;++rt)
#pragma unroll
          for (int ct=0;ct<2;++ct)
            acc[rt][ct] = __builtin_amdgcn_mfma_f32_16x16x32_f16(ah[rt][kc], cur[kc*2+ct], acc[rt][ct], 0,0,0);

#pragma unroll
      for (int ct=0;ct<2;++ct){
        const int cid = g*2 + ct;                      // global code = cid*16+col
#pragma unroll
        for (int rt=0;rt<2;++rt)
#pragma unroll
          for (int rg=0;rg<4;++rg){
            float sc = fmaf(-2.0f, acc[rt][ct][rg], ccc[ct]);
            unsigned u = (__builtin_bit_cast(unsigned, sc) & ~63u) | (unsigned)cid;
            float sp = __builtin_bit_cast(float, u);
            if (sp < p1[rt][rg]) { p2[rt][rg]=p1[rt][rg]; p1[rt][rg]=sp; }
            else if (sp < p2[rt][rg]) { p2[rt][rg]=sp; }
          }
      }
    }

    // ---- publish per-lane packed top-2 (wave-private, lockstep) ----
#pragma unroll
    for (int rt=0;rt<2;++rt)
#pragma unroll
      for (int rg=0;rg<4;++rg){
        const int row = rt*16 + quad*4 + rg;
        sCS[wv][row][col*2+0] = p1[rt][rg];
        sCS[wv][row][col*2+1] = p2[rt][rg];
      }

    // ---- lanes 0..31: scan own row's 32 packed entries -> top-4 ids ----
    if (ln < 32){
      const int row = ln;
      float b0=3.0e38f,b1=3.0e38f,b2=3.0e38f,b3=3.0e38f;
      int   e0=0,e1=0,e2=0,e3=0;
#pragma unroll
      for (int c2=0;c2<32;++c2){
        const float sc = sCS[wv][row][c2];
        const int   id = (((__builtin_bit_cast(unsigned, sc)) & 63u)<<4) + (c2>>1);
        const bool l0 = (sc<b0);
        const bool l1 = (sc<b1);
        const bool l2 = (sc<b2);
        const bool l3 = (sc<b3);
        if (l3){
          b3 = l2 ? b2 : sc;  e3 = l2 ? e2 : id;
          if (l2){
            b2 = l1 ? b1 : sc;  e2 = l1 ? e1 : id;
            if (l1){
              b1 = l0 ? b0 : sc;  e1 = l0 ? e0 : id;
              if (l0){ b0 = sc; e0 = id; }
            }
          }
        }
      }
      sI4[wv][row][0]=e0; sI4[wv][row][1]=e1; sI4[wv][row][2]=e2; sI4[wv][row][3]=e3;
    }

    // ---- fp64 exact rescore of top-4, winner update (wave-private) ----------
#pragma unroll
    for (int rt=0;rt<2;++rt){
      const int m = rt*16 + col;
      double bestS = 1.0e300; int bestJ = 0x7fffffff;
#pragma unroll
      for (int cnd=0;cnd<4;++cnd){
        const int jj = sI4[wv][m][cnd];
        const float* p = cbq + ((size_t)jj<<7) + (quad<<3);
        double sd = 0.0;
#pragma unroll
        for (int kc=0;kc<4;++kc){
          float4_ a0 = *(const float4_*)(p + kc*32);
          float4_ a1 = *(const float4_*)(p + kc*32 + 4);
          float fv[8] = {a0.x,a0.y,a0.z,a0.w,a1.x,a1.y,a1.z,a1.w};
#pragma unroll
          for (int j=0;j<8;++j){
            double cd = (double)fv[j];
            sd += cd*(cd - 2.0*rmast[rt][kc][j]);
          }
        }
        sd += __shfl_xor(sd, 16); sd += __shfl_xor(sd, 32);
        if ((sd < bestS) || (sd == bestS && jj < bestJ)){ bestS = sd; bestJ = jj; }
      }
      const float* pw = cbq + ((size_t)bestJ<<7) + (quad<<3);
#pragma unroll
      for (int kc=0;kc<4;++kc){
        float4_ w0 = *(const float4_*)(pw + kc*32);
        float4_ w1 = *(const float4_*)(pw + kc*32 + 4);
        float fw[8] = {w0.x,w0.y,w0.z,w0.w,w1.x,w1.y,w1.z,w1.w};
#pragma unroll
        for (int j=0;j<8;++j){
          double rn = rmast[rt][kc][j] - (double)fw[j];
          rmast[rt][kc][j] = rn;
          lossd += rn*rn;
        }
      }
    }
    makeAB();
  }

  // ---- epilogue: quantized = x - r_final ----
#pragma unroll
  for (int rt=0;rt<2;++rt){
    const int t = t0 + rt*16 + col;
#pragma unroll
    for (int kc=0;kc<4;++kc)
#pragma unroll
      for (int j=0;j<8;++j){
        const int d = kc*32 + quad*8 + j;
        const size_t o = ((size_t)b*D_ + d)*T_ + t;
        out[o] = (float)((double)x[o] - rmast[rt][kc][j]);
      }
  }
#pragma unroll
  for (int mk=1; mk<64; mk<<=1) lossd += __shfl_xor(lossd, mk);
  if (ln==0) atomicAdd(lossAcc, lossd);
}

__global__ void rvq_fin(const double* __restrict__ lossAcc, float* __restrict__ out){
  out[(size_t)B_*D_*T_] = (float)(*lossAcc * (1.0/((double)B_*(double)D_*(double)T_)));
}

extern "C" void kernel_launch(void* const* d_in, const int* in_sizes, int n_in,
                              void* d_out, int out_size, void* d_ws, size_t ws_size,
                              hipStream_t stream) {
  const float* x  = (const float*)d_in[0];   // [B, D, T] fp32
  const float* cb = (const float*)d_in[1];   // [Q, C, D] fp32
  float* out      = (float*)d_out;           // [B*D*T] quantized + [1] loss
  double* lossAcc = (double*)d_ws;
  float*  sumsq   = (float*)((char*)d_ws + 256);   // Q*C floats

  hipMemsetAsync(d_ws, 0, 256, stream);
  rvq_prep<<<Q_*C_/128, 256, 0, stream>>>(cb, sumsq);
  rvq_h   <<<(Q_*C_*D_)/(256*8), 256, 0, stream>>>(cb);
  rvq_main<<<(B_*T_)/128, 256, 0, stream>>>(x, cb, sumsq, lossAcc, out);
  rvq_fin <<<1, 1, 0, stream>>>(lossAcc, out);
}